// Round 3
// baseline (180.589 us; speedup 1.0000x reference)
//
#include <hip/hip_runtime.h>
#include <cstdint>
#include <cstddef>

#define BT_TOTAL 76800            // 128*600 cells
#define NITEMS   (BT_TOTAL * 6)   // 460800 (cell,pair) items
#define NTHR     256
#define NBLK     (NITEMS / NTHR)  // 1800 exactly, no tail
#define NCLS     13
#define IGN      (-100)

struct Partial { float ls; int lc; int cor; int val; };

// ====== Flat kernel: one lane per (cell,pair). No LDS staging, no barriers, no DMA. ======
extern "C" __global__ __launch_bounds__(NTHR, 5)
void tdoa_flat(const float* __restrict__ pred, const float* __restrict__ target,
               Partial* __restrict__ part) {
    const int tid  = threadIdx.x;
    const int gid  = blockIdx.x * NTHR + tid;
    const int cell = gid / 6;
    const int p    = gid - cell * 6;

    const float* tg = target + (size_t)cell * 195;   // [e][f][c] : e*65 + f*13 + c
    const float* pp = pred   + (size_t)cell * 234 + p; // [c][tr][p] strides 18,6,1

    // ---- phase 1 (in-lane): TDOA for THIS pair only (2 mics, 2 sqrt per track) ----
    const float MX[4] = { 0.02432757455f,  0.02432757455f, -0.02432757455f, -0.02432757455f };
    const float MY[4] = { 0.02432757455f, -0.02432757455f,  0.02432757455f, -0.02432757455f };
    const float MZ[4] = { 0.02409021033f, -0.02409021033f, -0.02409021033f,  0.02409021033f };
    const int PI_[6] = {0,0,0,1,1,2};
    const int PJ_[6] = {1,2,3,2,3,3};
    const int mi = PI_[p], mj = PJ_[p];
    const float mxi = MX[mi], myi = MY[mi], mzi = MZ[mi];
    const float mxj = MX[mj], myj = MY[mj], mzj = MZ[mj];

    int  td[3];
    bool ab[3];
    int  nact = 0;
#pragma unroll
    for (int e = 0; e < 3; e++) {
        // <=1 active class per (cell,track) by construction: find it
        float av = 0.f; int ci = 0; bool ia = false;
#pragma unroll
        for (int c = 0; c < NCLS; c++) {
            const float a = tg[e * 65 + c];
            const bool  g = (a > 0.0f);
            av = g ? a : av;
            ci = g ? c : ci;
            ia = ia || g;
        }
        // dot(a, doa/dist) == av * row[ci] for one-hot a; av=0 row=0 when inactive
        const float d0 = av * tg[e * 65 + 13 + ci];
        const float d1 = av * tg[e * 65 + 26 + ci];
        const float d2 = av * tg[e * 65 + 39 + ci];
        const float ds = av * tg[e * 65 + 52 + ci];
        const float sx = d0 * ds, sy = d1 * ds, sz = d2 * ds;
        const float exi = sx - mxi, eyi = sy - myi, ezi = sz - mzi;
        const float exj = sx - mxj, eyj = sy - myj, ezj = sz - mzj;
        const float dmi = sqrtf(exi * exi + eyi * eyi + ezi * ezi);
        const float dmj = sqrtf(exj * exj + eyj * eyj + ezj * ezj);
        td[e] = (int)rintf((dmi - dmj) * (24000.0f / 343.0f)) + 6;   // MAX_TAU=6
        ab[e] = ia;
        nact += ia ? 1 : 0;
    }

    // stable argsort(!is_active) for E=3: actives first, original order
    const int g0 = ab[0] ? td[0] : (ab[1] ? td[1] : td[2]);
    const int g1 = (ab[0] && ab[1]) ? td[1] : td[2];
    const int g2 = td[2];
    int ta[3], tb[3];
    ta[0] = g0;
    ta[1] = (nact >= 2) ? g1 : g0;
    ta[2] = (nact == 3) ? g2 : ((nact == 2) ? g1 : g0);
    tb[0] = g0;
    tb[1] = (nact >= 2) ? g1 : g0;
    tb[2] = (nact == 3) ? g2 : g0;
    if (nact == 0) { ta[0] = ta[1] = ta[2] = IGN; tb[0] = tb[1] = tb[2] = IGN; }

    // ---- phase 2 (in-lane): softmax + PIT over this item's 13x3 logits ----
    float x[NCLS][3];
#pragma unroll
    for (int c = 0; c < NCLS; c++)
#pragma unroll
        for (int j = 0; j < 3; j++)
            x[c][j] = pp[c * 18 + j * 6];

    int   am[3];
    float lse[3];
#pragma unroll
    for (int j = 0; j < 3; j++) {
        float m = x[0][j]; int a = 0;
#pragma unroll
        for (int c = 1; c < NCLS; c++) { if (x[c][j] > m) { m = x[c][j]; a = c; } }
        float s = 0.f;
#pragma unroll
        for (int c = 0; c < NCLS; c++) s += expf(x[c][j] - m);
        am[j] = a; lse[j] = m + logf(s);
    }

    // indexed L1-hot global re-reads instead of 13-deep cndmask chains
    float La[3][3], Lb[3][3];
#pragma unroll
    for (int i = 0; i < 3; i++) {
        const int  ca  = (ta[i] < 0) ? 0 : ta[i];
        const int  cbb = (tb[i] < 0) ? 0 : tb[i];
        const bool ia2 = (ta[i] == IGN);
        const bool ib2 = (tb[i] == IGN);
#pragma unroll
        for (int j = 0; j < 3; j++) {
            La[i][j] = ia2 ? 0.f : (lse[j] - pp[ca  * 18 + j * 6]);
            Lb[i][j] = ib2 ? 0.f : (lse[j] - pp[cbb * 18 + j * 6]);
        }
    }

    const int P0[6] = {0,0,1,1,2,2};
    const int P1[6] = {1,2,0,2,0,1};
    const int P2[6] = {2,1,2,0,1,0};
    float l1 = 0.f, l2 = 0.f; int i1 = 0, i2 = 0;
#pragma unroll
    for (int q = 0; q < 6; q++) {
        const float va = (La[0][P0[q]] + La[1][P1[q]] + La[2][P2[q]]) * (1.0f / 3.0f);
        const float vb = (Lb[0][P0[q]] + Lb[1][P1[q]] + Lb[2][P2[q]]) * (1.0f / 3.0f);
        if (q == 0) { l1 = va; l2 = vb; }
        else {
            if (va < l1) { l1 = va; i1 = q; }
            if (vb < l2) { l2 = vb; i2 = q; }
        }
    }

    const bool use2 = (l2 < l1);
    const float loss = use2 ? l2 : l1;
    const int  qsel = use2 ? i2 : i1;
    const int PK[6] = {36, 24, 33, 9, 18, 6};   // p0 | p1<<2 | p2<<4
    int pk = PK[0];
#pragma unroll
    for (int k = 1; k < 6; k++) pk = (qsel == k) ? PK[k] : pk;
    const int s0 = use2 ? tb[0] : ta[0];
    const int s1 = use2 ? tb[1] : ta[1];
    const int s2 = use2 ? tb[2] : ta[2];

    float lsum = 0.f;
    int   lcnt = 0, cor = 0, nval = 0;
#pragma unroll
    for (int i = 0; i < 3; i++) {
        const int pi = (pk >> (2 * i)) & 3;
        const int tp = (pi == 0) ? s0 : ((pi == 1) ? s1 : s2);
        const bool v = (tp != IGN);
        nval += v ? 1 : 0;
        cor  += (v && (am[i] == tp)) ? 1 : 0;
    }
    if (loss > 0.f) { lsum += loss; lcnt++; }

    // block reduction (4 waves) -> per-block partial, NO atomics
#pragma unroll
    for (int off = 32; off > 0; off >>= 1) {
        lsum += __shfl_down(lsum, off, 64);
        lcnt += __shfl_down(lcnt, off, 64);
        cor  += __shfl_down(cor,  off, 64);
        nval += __shfl_down(nval, off, 64);
    }
    __shared__ float rf[4];
    __shared__ int   r1[4], r2[4], r3[4];
    const int wid = tid >> 6;
    if ((tid & 63) == 0) { rf[wid] = lsum; r1[wid] = lcnt; r2[wid] = cor; r3[wid] = nval; }
    __syncthreads();
    if (tid == 0) {
        Partial pt;
        pt.ls  = rf[0] + rf[1] + rf[2] + rf[3];
        pt.lc  = r1[0] + r1[1] + r1[2] + r1[3];
        pt.cor = r2[0] + r2[1] + r2[2] + r2[3];
        pt.val = r3[0] + r3[1] + r3[2] + r3[3];
        part[blockIdx.x] = pt;
    }
}

// ================= Final reduce =================
extern "C" __global__ __launch_bounds__(256)
void tdoa_final(const Partial* __restrict__ part, float* __restrict__ out) {
    const int tid = threadIdx.x;
    double ls = 0.0; int lc = 0, cor = 0, val = 0;
    for (int i = tid; i < NBLK; i += 256) {
        const Partial p = part[i];
        ls += (double)p.ls; lc += p.lc; cor += p.cor; val += p.val;
    }
#pragma unroll
    for (int off = 32; off > 0; off >>= 1) {
        ls  += __shfl_down(ls,  off, 64);
        lc  += __shfl_down(lc,  off, 64);
        cor += __shfl_down(cor, off, 64);
        val += __shfl_down(val, off, 64);
    }
    __shared__ double sd[4];
    __shared__ int    s1[4], s2[4], s3[4];
    const int wid = tid >> 6;
    if ((tid & 63) == 0) { sd[wid] = ls; s1[wid] = lc; s2[wid] = cor; s3[wid] = val; }
    __syncthreads();
    if (tid == 0) {
        const double L = sd[0] + sd[1] + sd[2] + sd[3];
        const int c1 = s1[0] + s1[1] + s1[2] + s1[3];
        const int c2 = s2[0] + s2[1] + s2[2] + s2[3];
        const int c3 = s3[0] + s3[1] + s3[2] + s3[3];
        out[0] = (c1 > 0) ? (float)(L / (double)c1) : 0.0f;
        out[1] = (c3 > 0) ? ((float)c2 / (float)c3) : 0.0f;
    }
}

extern "C" void kernel_launch(void* const* d_in, const int* in_sizes, int n_in,
                              void* d_out, int out_size, void* d_ws, size_t ws_size,
                              hipStream_t stream) {
    const float* pred   = (const float*)d_in[0];
    const float* target = (const float*)d_in[1];
    Partial* part = (Partial*)d_ws;   // 1800 * 16 B of scratch
    float* out = (float*)d_out;
    hipLaunchKernelGGL(tdoa_flat,  dim3(NBLK), dim3(NTHR), 0, stream, pred, target, part);
    hipLaunchKernelGGL(tdoa_final, dim3(1),    dim3(256), 0, stream, part, out);
}

// Round 4
// 155.988 us; speedup vs baseline: 1.1577x; 1.1577x over previous
//
#include <hip/hip_runtime.h>
#include <cstdint>
#include <cstddef>

#define BT_TOTAL 76800   // 128*600 cells
#define NCLS 13
#define IGN  (-100)

#define CPB   32                 // cells per block
#define NTHR  192                // 3 waves; items = CPB*6 = 192 = 100% lane density
#define NBLK  (BT_TOTAL / CPB)   // 2400
#define NF4P  (CPB * 234 / 4)    // 1872 float4 of pred per block
#define KP    10                 // ceil(1872/192) rounds, wave-uniform (clamped tail)
#define PADP  (KP * NTHR)        // 1920 float4 LDS (incl. 48 float4 pad)

struct Partial { float ls; int lc; int cor; int val; };

// async global->LDS DMA, 16B per lane; LDS dest = wave-uniform base + lane*16
__device__ __forceinline__ void stage16(const float4* g, float4* l) {
    __builtin_amdgcn_global_load_lds((const __attribute__((address_space(1))) void*)g,
                                     (__attribute__((address_space(3))) void*)l,
                                     16, 0, 0);
}

// ====== Fused kernel: DMA pred || in-lane TDOA from global, ONE drain, dense lanes ======
extern "C" __global__ __launch_bounds__(NTHR)
void tdoa_fused(const float* __restrict__ pred, const float* __restrict__ target,
                Partial* __restrict__ part) {
    const int tid = threadIdx.x;
    const int cb  = blockIdx.x * CPB;

    __shared__ float4 sP4[PADP];   // 30,720 B -> 5 blocks/CU, 15 waves/CU
    const float* sP = (const float*)sP4;

    // ---- issue pred DMA first; its latency hides under phase 1 below ----
    {
        const float4* gp = (const float4*)(pred + (size_t)cb * 234);
#pragma unroll
        for (int r = 0; r < KP; r++) {
            const int i  = r * NTHR + tid;
            const int ic = (i < NF4P) ? i : (NF4P - 1);  // clamp src; LDS dest linear (pad)
            stage16(gp + ic, &sP4[i]);
        }
    }

    // ---- phase 1 (in-lane, all 192 lanes): TDOA for THIS lane's pair only ----
    const int cell = tid / 6;          // 0..31
    const int p    = tid - cell * 6;   // 0..5
    const float* tg = target + (size_t)(cb + cell) * 195;   // [e][f][c] : e*65 + f*13 + c

    const float MX[4] = { 0.02432757455f,  0.02432757455f, -0.02432757455f, -0.02432757455f };
    const float MY[4] = { 0.02432757455f, -0.02432757455f,  0.02432757455f, -0.02432757455f };
    const float MZ[4] = { 0.02409021033f, -0.02409021033f, -0.02409021033f,  0.02409021033f };
    const int PI_[6] = {0,0,0,1,1,2};
    const int PJ_[6] = {1,2,3,2,3,3};
    const int mi = PI_[p], mj = PJ_[p];
    const float mxi = MX[mi], myi = MY[mi], mzi = MZ[mi];
    const float mxj = MX[mj], myj = MY[mj], mzj = MZ[mj];

    int  td[3];
    bool ab[3];
    int  nact = 0;
#pragma unroll
    for (int e = 0; e < 3; e++) {
        // <=1 active class per (cell,track) by construction: find it (one-hot trick)
        float av = 0.f; int ci = 0; bool ia = false;
#pragma unroll
        for (int c = 0; c < NCLS; c++) {
            const float a = tg[e * 65 + c];
            const bool  g = (a > 0.0f);
            av = g ? a : av;
            ci = g ? c : ci;
            ia = ia || g;
        }
        const float d0 = av * tg[e * 65 + 13 + ci];
        const float d1 = av * tg[e * 65 + 26 + ci];
        const float d2 = av * tg[e * 65 + 39 + ci];
        const float ds = av * tg[e * 65 + 52 + ci];
        const float sx = d0 * ds, sy = d1 * ds, sz = d2 * ds;
        const float exi = sx - mxi, eyi = sy - myi, ezi = sz - mzi;
        const float exj = sx - mxj, eyj = sy - myj, ezj = sz - mzj;
        const float dmi = sqrtf(exi * exi + eyi * eyi + ezi * ezi);
        const float dmj = sqrtf(exj * exj + eyj * eyj + ezj * ezj);
        td[e] = (int)rintf((dmi - dmj) * (24000.0f / 343.0f)) + 6;   // MAX_TAU=6
        ab[e] = ia;
        nact += ia ? 1 : 0;
    }

    // stable argsort(!is_active) for E=3: actives first, original order
    const int g0 = ab[0] ? td[0] : (ab[1] ? td[1] : td[2]);
    const int g1 = (ab[0] && ab[1]) ? td[1] : td[2];
    const int g2 = td[2];
    int ta[3], tb[3];
    ta[0] = g0;
    ta[1] = (nact >= 2) ? g1 : g0;
    ta[2] = (nact == 3) ? g2 : ((nact == 2) ? g1 : g0);
    tb[0] = g0;
    tb[1] = (nact >= 2) ? g1 : g0;
    tb[2] = (nact == 3) ? g2 : g0;
    if (nact == 0) { ta[0] = ta[1] = ta[2] = IGN; tb[0] = tb[1] = tb[2] = IGN; }

    __syncthreads();   // single drain (compiler emits vmcnt(0)); DMA latency was covered above

    // ---- phase 2 (all 192 lanes): softmax + PIT from LDS ----
    const float* pp = sP + cell * 234 + p;   // [c][tr][p] strides 18,6,1

    float x[NCLS][3];
#pragma unroll
    for (int c = 0; c < NCLS; c++)
#pragma unroll
        for (int j = 0; j < 3; j++)
            x[c][j] = pp[c * 18 + j * 6];

    int   am[3];
    float lse[3];
#pragma unroll
    for (int j = 0; j < 3; j++) {
        float m = x[0][j]; int a = 0;
#pragma unroll
        for (int c = 1; c < NCLS; c++) { if (x[c][j] > m) { m = x[c][j]; a = c; } }
        float s = 0.f;
#pragma unroll
        for (int c = 0; c < NCLS; c++) s += expf(x[c][j] - m);
        am[j] = a; lse[j] = m + logf(s);
    }

    // indexed LDS reads instead of 13-deep cndmask select chains
    float La[3][3], Lb[3][3];
#pragma unroll
    for (int i = 0; i < 3; i++) {
        const int  ca  = (ta[i] < 0) ? 0 : ta[i];
        const int  cbb = (tb[i] < 0) ? 0 : tb[i];
        const bool ia2 = (ta[i] == IGN);
        const bool ib2 = (tb[i] == IGN);
#pragma unroll
        for (int j = 0; j < 3; j++) {
            La[i][j] = ia2 ? 0.f : (lse[j] - pp[ca  * 18 + j * 6]);
            Lb[i][j] = ib2 ? 0.f : (lse[j] - pp[cbb * 18 + j * 6]);
        }
    }

    const int P0[6] = {0,0,1,1,2,2};
    const int P1[6] = {1,2,0,2,0,1};
    const int P2[6] = {2,1,2,0,1,0};
    float l1 = 0.f, l2 = 0.f; int i1 = 0, i2 = 0;
#pragma unroll
    for (int q = 0; q < 6; q++) {
        const float va = (La[0][P0[q]] + La[1][P1[q]] + La[2][P2[q]]) * (1.0f / 3.0f);
        const float vb = (Lb[0][P0[q]] + Lb[1][P1[q]] + Lb[2][P2[q]]) * (1.0f / 3.0f);
        if (q == 0) { l1 = va; l2 = vb; }
        else {
            if (va < l1) { l1 = va; i1 = q; }
            if (vb < l2) { l2 = vb; i2 = q; }
        }
    }

    const bool use2 = (l2 < l1);
    const float loss = use2 ? l2 : l1;
    const int  qsel = use2 ? i2 : i1;
    const int PK[6] = {36, 24, 33, 9, 18, 6};   // p0 | p1<<2 | p2<<4
    int pk = PK[0];
#pragma unroll
    for (int k = 1; k < 6; k++) pk = (qsel == k) ? PK[k] : pk;
    const int s0 = use2 ? tb[0] : ta[0];
    const int s1 = use2 ? tb[1] : ta[1];
    const int s2 = use2 ? tb[2] : ta[2];

    float lsum = 0.f;
    int   lcnt = 0, cor = 0, nval = 0;
#pragma unroll
    for (int i = 0; i < 3; i++) {
        const int pi = (pk >> (2 * i)) & 3;
        const int tp = (pi == 0) ? s0 : ((pi == 1) ? s1 : s2);
        const bool v = (tp != IGN);
        nval += v ? 1 : 0;
        cor  += (v && (am[i] == tp)) ? 1 : 0;
    }
    if (loss > 0.f) { lsum += loss; lcnt++; }

    // block reduction (3 waves) -> per-block partial, NO atomics
#pragma unroll
    for (int off = 32; off > 0; off >>= 1) {
        lsum += __shfl_down(lsum, off, 64);
        lcnt += __shfl_down(lcnt, off, 64);
        cor  += __shfl_down(cor,  off, 64);
        nval += __shfl_down(nval, off, 64);
    }
    __shared__ float rf[3];
    __shared__ int   r1[3], r2[3], r3[3];
    const int wid = tid >> 6;
    if ((tid & 63) == 0) { rf[wid] = lsum; r1[wid] = lcnt; r2[wid] = cor; r3[wid] = nval; }
    __syncthreads();
    if (tid == 0) {
        Partial pt;
        pt.ls  = rf[0] + rf[1] + rf[2];
        pt.lc  = r1[0] + r1[1] + r1[2];
        pt.cor = r2[0] + r2[1] + r2[2];
        pt.val = r3[0] + r3[1] + r3[2];
        part[blockIdx.x] = pt;
    }
}

// ================= Final reduce =================
extern "C" __global__ __launch_bounds__(256)
void tdoa_final(const Partial* __restrict__ part, float* __restrict__ out) {
    const int tid = threadIdx.x;
    double ls = 0.0; int lc = 0, cor = 0, val = 0;
    for (int i = tid; i < NBLK; i += 256) {
        const Partial p = part[i];
        ls += (double)p.ls; lc += p.lc; cor += p.cor; val += p.val;
    }
#pragma unroll
    for (int off = 32; off > 0; off >>= 1) {
        ls  += __shfl_down(ls,  off, 64);
        lc  += __shfl_down(lc,  off, 64);
        cor += __shfl_down(cor, off, 64);
        val += __shfl_down(val, off, 64);
    }
    __shared__ double sd[4];
    __shared__ int    s1[4], s2[4], s3[4];
    const int wid = tid >> 6;
    if ((tid & 63) == 0) { sd[wid] = ls; s1[wid] = lc; s2[wid] = cor; s3[wid] = val; }
    __syncthreads();
    if (tid == 0) {
        const double L = sd[0] + sd[1] + sd[2] + sd[3];
        const int c1 = s1[0] + s1[1] + s1[2] + s1[3];
        const int c2 = s2[0] + s2[1] + s2[2] + s2[3];
        const int c3 = s3[0] + s3[1] + s3[2] + s3[3];
        out[0] = (c1 > 0) ? (float)(L / (double)c1) : 0.0f;
        out[1] = (c3 > 0) ? ((float)c2 / (float)c3) : 0.0f;
    }
}

extern "C" void kernel_launch(void* const* d_in, const int* in_sizes, int n_in,
                              void* d_out, int out_size, void* d_ws, size_t ws_size,
                              hipStream_t stream) {
    const float* pred   = (const float*)d_in[0];
    const float* target = (const float*)d_in[1];
    Partial* part = (Partial*)d_ws;   // 2400 * 16 B of scratch
    float* out = (float*)d_out;
    hipLaunchKernelGGL(tdoa_fused, dim3(NBLK), dim3(NTHR), 0, stream, pred, target, part);
    hipLaunchKernelGGL(tdoa_final, dim3(1),    dim3(256), 0, stream, part, out);
}